// Round 6
// baseline (279.462 us; speedup 1.0000x reference)
//
#include <hip/hip_runtime.h>
#include <hip/hip_bf16.h>

typedef _Float16 half8 __attribute__((ext_vector_type(8)));
typedef float floatx4 __attribute__((ext_vector_type(4)));

#define LOG2E 1.44269504088896340736f

// DPP cross-lane max within quads (pooling over corner = lane&3), no DS pipe
__device__ __forceinline__ float pool4_dpp(float v) {
  int s1 = __builtin_amdgcn_update_dpp(0, __float_as_int(v), 0xB1, 0xF, 0xF, true); // xor1
  float v1 = fmaxf(v, __int_as_float(s1));
  int s2 = __builtin_amdgcn_update_dpp(0, __float_as_int(v1), 0x4E, 0xF, 0xF, true); // xor2
  return fmaxf(v1, __int_as_float(s2));
}

// monotonic float<->uint mapping for atomicMax over signed floats
__device__ __forceinline__ unsigned f2mono(float f) {
  unsigned u = __float_as_uint(f);
  return (u & 0x80000000u) ? ~u : (u | 0x80000000u);
}
__device__ __forceinline__ float mono2f(unsigned u) {
  return (u & 0x80000000u) ? __uint_as_float(u & 0x7fffffffu)
                           : __uint_as_float(~u);
}

// ---------------- prep: f16 MLP weights + conv B-matrices (+ emx init)
__global__ __launch_bounds__(256) void k_prep(const float* __restrict__ Wf1,
    const float* __restrict__ Wf2, const float* __restrict__ Wg,
    const float* __restrict__ W1, const float* __restrict__ W2,
    _Float16* __restrict__ w1f, _Float16* __restrict__ w2f,
    _Float16* __restrict__ wgf, _Float16* __restrict__ B1,
    _Float16* __restrict__ B2M, unsigned* __restrict__ emx) {
  const int i = blockIdx.x * 256 + threadIdx.x;
  if (i == 0) emx[0] = 0u;  // f2mono lower bound
  if (i < 53248) {
    const int n = i / 416, k = i - n * 416;
    w1f[i] = (_Float16)((n < 120 && k < 400) ? Wf1[n * 400 + k] : 0.f);
  } else if (i < 65536) {
    const int j = i - 53248;
    const int n = j >> 7, k = j & 127;
    w2f[j] = (_Float16)((n < 84 && k < 120) ? Wf2[n * 120 + k] : 0.f);
  } else if (i < 67072) {
    const int g = i - 65536;
    const int n = g / 96, k = g - n * 96;
    wgf[g] = (_Float16)((n < 10 && k < 84) ? Wg[n * 84 + k] : 0.f);
  } else if (i < 73216) {
    const int g = i - 67072;
    const int n = g / 192, k = g - n * 192;
    const int co = n >> 2, cy = (n >> 1) & 1, cx = n & 1;
    const int pidx = k >> 3, j = k & 7;
    const int r = pidx >> 2, ci = pidx & 3;
    float v = 0.f;
    if (co < 6 && ci < 3) {
      const int ky = r - cy, kx = j - cx;
      if (ky >= 0 && ky < 5 && kx >= 0 && kx < 5)
        v = W1[((co * 3 + ci) * 5 + ky) * 5 + kx];
    }
    B1[g] = (_Float16)v;
  } else if (i < 77312) {
    const int g = i - 73216;
    const int n = g >> 8, k = g & 255;
    float v = 0.f;
    if (k < 240) {
      const int ci = k / 40, rem = k - ci * 40, r = rem >> 3, j = rem & 7;
      if (j < 5) v = W2[((n * 6 + ci) * 5 + r) * 5 + j];
    }
    B2M[g] = (_Float16)v;
  }
}

// ---------------- fused conv1+pool+conv2+pool: 2 images/block, 256 threads.
// LDS 17792 B -> 8 blocks/CU (32 waves) with VGPR<=64 (__launch_bounds__(256,8)).
// Single input copy (no alignment duplicate): A-fragments read as 4x ds_read_b32
// (4B-aligned always). Per image (stride 6544B):
//   conv1 staging: 3 ci x 2180B (32 rows x 68B = 32 cols f16 + 2 zero cols)
//   conv2 staging (ALIASES conv1 region after barrier): 6 ci x 1016B =
//     2 parity copies x 508B (14 rows x 36B), copy1 shifted by one f16
// h1 region at 13088: 2 img x 1176 f16 (2352B).
__global__ __launch_bounds__(256, 8) void k_convs(const float* __restrict__ x,
    const _Float16* __restrict__ B1, const float* __restrict__ b1,
    const _Float16* __restrict__ B2M, const float* __restrict__ b2,
    _Float16* __restrict__ h2) {
  __shared__ __align__(16) char sm[17792];
  _Float16* h1L = (_Float16*)(sm + 13088);
  const int t = threadIdx.x;
  const int n0 = blockIdx.x * 2;
  const int w4 = t >> 6, lane = t & 63;
  const int l16 = lane & 15, q = lane >> 4;

  // ---- phase 0: stage 2 input images, single f16 copy
  const float4* x4 = (const float4*)(x + (size_t)n0 * 3072);
  for (int i = t; i < 1536; i += 256) {
    const float4 v = x4[i];
    const int img = (i >= 768);
    const int ii = i - img * 768;
    const int ci = ii >> 8, rem2 = ii & 255;
    const int y = rem2 >> 3, c = rem2 & 7;
    union { _Float16 h[2]; unsigned u; } p01, p23;
    p01.h[0] = (_Float16)v.x; p01.h[1] = (_Float16)v.y;
    p23.h[0] = (_Float16)v.z; p23.h[1] = (_Float16)v.w;
    char* row = sm + img * 6544 + ci * 2180 + y * 68;
    *(unsigned*)(row + 8 * c) = p01.u;
    *(unsigned*)(row + 8 * c + 4) = p23.u;
  }
  if (t < 192) {  // zero cols 32,33 of each row (NaN guard for j>=5 taps)
    const int img = t / 96, tt = t - img * 96;
    const int ci = tt >> 5, y = tt & 31;
    *(unsigned*)(sm + img * 6544 + ci * 2180 + y * 68 + 64) = 0u;
  }
  if (t < 32) {  // h2 tail padding (cols 400..415)
    const int im = t >> 4;
    h2[(size_t)(n0 + im) * 416 + 400 + (t & 15)] = (_Float16)0.f;
  }
  __syncthreads();

  // ---- phase 1: conv1 + relu + pool -> h1 in LDS.
  // wave = (img = w4>>1, half = w4&1 -> 7 py rows). Two nt passes (n-tiles
  // 0..15 / 16..31) to halve live B-fragment registers.
  {
    const int img = w4 >> 1, wl = w4 & 1;
    const char* base = sm + img * 6544 + ((q == 3) ? 0 : q * 2180) + 4 * l16;
    const int py0 = wl * 7;
    const bool store_lane = (l16 & 3) == 0;
    for (int nt = 0; nt < 2; nt++) {
      const int co = nt * 4 + (l16 >> 2);
      half8 bfr[6];
#pragma unroll
      for (int kc = 0; kc < 6; kc++)
        bfr[kc] = *(const half8*)(B1 + (size_t)(nt * 16 + l16) * 192 + kc * 32 + q * 8);
      const float bias = (co < 6) ? b1[co] : 0.f;
      union AU { unsigned u[4]; half8 h; } a[6];
#pragma unroll
      for (int r = 0; r < 6; r++) {
        const char* rp = base + (2 * py0 + r) * 68;
        a[r].u[0] = *(const unsigned*)(rp);
        a[r].u[1] = *(const unsigned*)(rp + 4);
        a[r].u[2] = *(const unsigned*)(rp + 8);
        a[r].u[3] = *(const unsigned*)(rp + 12);
      }
      for (int py = py0; py < py0 + 7; ++py) {
        floatx4 acc;
#pragma unroll
        for (int r = 0; r < 4; r++) acc[r] = 0.f;
#pragma unroll
        for (int kc = 0; kc < 6; kc++)
          acc = __builtin_amdgcn_mfma_f32_16x16x32_f16(a[kc].h, bfr[kc], acc, 0, 0, 0);
        if (py < py0 + 6) {
          a[0] = a[2]; a[1] = a[3]; a[2] = a[4]; a[3] = a[5];
          const char* rp4 = base + (2 * py + 6) * 68;
          a[4].u[0] = *(const unsigned*)(rp4);
          a[4].u[1] = *(const unsigned*)(rp4 + 4);
          a[4].u[2] = *(const unsigned*)(rp4 + 8);
          a[4].u[3] = *(const unsigned*)(rp4 + 12);
          const char* rp5 = rp4 + 68;
          a[5].u[0] = *(const unsigned*)(rp5);
          a[5].u[1] = *(const unsigned*)(rp5 + 4);
          a[5].u[2] = *(const unsigned*)(rp5 + 8);
          a[5].u[3] = *(const unsigned*)(rp5 + 12);
        }
        float p0[4];
#pragma unroll
        for (int r = 0; r < 4; r++)
          p0[r] = fmaxf(pool4_dpp(acc[r]) + bias, 0.f);
        if (store_lane && co < 6) {
          union { _Float16 h[2]; unsigned u; } s01, s23;
          s01.h[0] = (_Float16)p0[0]; s01.h[1] = (_Float16)p0[1];
          s23.h[0] = (_Float16)p0[2]; s23.h[1] = (_Float16)p0[3];
          _Float16* dst = h1L + img * 1176 + co * 196 + py * 14 + q * 4;
          *(unsigned*)dst = s01.u;
          if (q < 3) *(unsigned*)(dst + 2) = s23.u;
        }
      }
    }
  }
  __syncthreads();

  // ---- phase 2: conv2 parity-staging (2 copies), overwrites conv1 region.
  // unit = (img, ci, y, g): writes dwords [4g,4g+4) of copy0 and copy1.
  for (int uu = t; uu < 336; uu += 256) {
    const int img = uu / 168, rem = uu - img * 168;
    const int ci = rem / 28, r2 = rem - ci * 28;
    const int y = r2 >> 1, g = r2 & 1;
    const unsigned* src = (const unsigned*)(h1L + img * 1176 + ci * 196 + y * 14);
    unsigned u5[5];
#pragma unroll
    for (int k = 0; k < 5; k++) {
      const int idx = 4 * g + k;
      u5[k] = (idx < 7) ? src[idx] : 0u;
    }
    char* b0 = sm + img * 6544 + ci * 1016 + y * 36 + 16 * g;
#pragma unroll
    for (int w = 0; w < 4; w++) {
      *(unsigned*)(b0 + 4 * w) = u5[w];
      *(unsigned*)(b0 + 508 + 4 * w) = (u5[w] >> 16) | (u5[w + 1] << 16);
    }
  }
  __syncthreads();

  // ---- phase 3: conv2 + relu + pool -> h2 global (13 m-tiles over 4 waves)
  {
    int C2[8];
#pragma unroll
    for (int kc = 0; kc < 8; kc++) {
      const int pidx = kc * 4 + q;
      C2[kc] = (pidx < 30) ? (pidx / 5) * 1016 + (pidx % 5) * 36 : 0;
    }
    const float bias2 = b2[l16];
    for (int mt = w4; mt < 13; mt += 4) {
      const int m = min(mt * 16 + l16, 199);
      const int pos = m >> 2, cy = (m >> 1) & 1, cx = m & 1;
      const int img = pos / 25, p = pos - img * 25;
      const int py = p / 5, px = p - py * 5;
      const char* base =
          sm + img * 6544 + cx * 508 + (2 * py + cy) * 36 + 4 * px;
      floatx4 acc;
#pragma unroll
      for (int r = 0; r < 4; r++) acc[r] = 0.f;
#pragma unroll
      for (int kc = 0; kc < 8; kc++) {
        union { unsigned u[4]; half8 h; } av;
        const char* ap = base + C2[kc];
        av.u[0] = *(const unsigned*)(ap);
        av.u[1] = *(const unsigned*)(ap + 4);
        av.u[2] = *(const unsigned*)(ap + 8);
        av.u[3] = *(const unsigned*)(ap + 12);
        const half8 bv = *(const half8*)(B2M + (size_t)l16 * 256 + kc * 32 + q * 8);
        acc = __builtin_amdgcn_mfma_f32_16x16x32_f16(av.h, bv, acc, 0, 0, 0);
      }
      const float v = fmaxf(fmaxf(acc[0], acc[1]), fmaxf(acc[2], acc[3]));
      const int posL = mt * 4 + q;
      if (posL < 50) {
        const int im = posL / 25, pp = posL - im * 25;
        h2[(size_t)(n0 + im) * 416 + l16 * 25 + pp] =
            (_Float16)fmaxf(v + bias2, 0.f);
      }
    }
  }
}

// ---------------- fused MLP via f16 MFMA; emits zT f16 [16][8192] (row10=ones),
// el/er pre-scaled by log2(e), and global el-max via atomicMax (mono encoding).
__global__ __launch_bounds__(256) void k_mlp(
    const _Float16* __restrict__ h2, const _Float16* __restrict__ w1,
    const float* __restrict__ bf1, const _Float16* __restrict__ w2,
    const float* __restrict__ bf2, const _Float16* __restrict__ wg,
    const float* __restrict__ al, const float* __restrict__ ar,
    _Float16* __restrict__ zT, float* __restrict__ el, float* __restrict__ er,
    unsigned* __restrict__ emx) {
  __shared__ __align__(16) _Float16 h3s[32 * 136];
  __shared__ __align__(16) _Float16 h4s[32 * 104];
  __shared__ float zs[32 * 17];
  const int t = threadIdx.x;
  const int w = t >> 6, lane = t & 63;
  const int l16 = lane & 15, q = lane >> 4;
  const int row0 = blockIdx.x * 32;
  for (int i = t; i < 2176; i += 256) ((float*)h3s)[i] = 0.f;
  for (int i = t; i < 1664; i += 256) ((float*)h4s)[i] = 0.f;
  const int rt = w & 1, cg = w >> 1;
  const int am = row0 + rt * 16 + l16;
  floatx4 acc[4];
#pragma unroll
  for (int ct = 0; ct < 4; ct++)
#pragma unroll
    for (int r = 0; r < 4; r++) acc[ct][r] = 0.f;
  const half8* Ag = (const half8*)(h2 + (size_t)am * 416 + q * 8);
  for (int kc = 0; kc < 13; kc++) {
    half8 a = Ag[kc * 4];
#pragma unroll
    for (int ct = 0; ct < 4; ct++) {
      const int n = cg * 64 + ct * 16 + l16;
      half8 b = *(const half8*)(w1 + (size_t)n * 416 + kc * 32 + q * 8);
      acc[ct] = __builtin_amdgcn_mfma_f32_16x16x32_f16(a, b, acc[ct], 0, 0, 0);
    }
  }
  __syncthreads();
#pragma unroll
  for (int ct = 0; ct < 4; ct++) {
    const int n = cg * 64 + ct * 16 + l16;
    if (n < 120) {
      const float bias = bf1[n];
#pragma unroll
      for (int r = 0; r < 4; r++) {
        const int rr = rt * 16 + q * 4 + r;
        h3s[rr * 136 + n] = (_Float16)fmaxf(acc[ct][r] + bias, 0.f);
      }
    }
  }
  __syncthreads();
  const int cbase2 = (w >> 1) * 3;
  floatx4 acc2[3];
#pragma unroll
  for (int ct = 0; ct < 3; ct++)
#pragma unroll
    for (int r = 0; r < 4; r++) acc2[ct][r] = 0.f;
  const _Float16* A2 = h3s + (rt * 16 + l16) * 136 + q * 8;
  for (int kc = 0; kc < 4; kc++) {
    half8 a = *(const half8*)(A2 + kc * 32);
#pragma unroll
    for (int ct = 0; ct < 3; ct++) {
      const int n = (cbase2 + ct) * 16 + l16;
      half8 b = *(const half8*)(w2 + (size_t)n * 128 + kc * 32 + q * 8);
      acc2[ct] = __builtin_amdgcn_mfma_f32_16x16x32_f16(a, b, acc2[ct], 0, 0, 0);
    }
  }
  __syncthreads();
#pragma unroll
  for (int ct = 0; ct < 3; ct++) {
    const int n = (cbase2 + ct) * 16 + l16;
    if (n < 84) {
      const float bias = bf2[n];
#pragma unroll
      for (int r = 0; r < 4; r++) {
        const int rr = rt * 16 + q * 4 + r;
        h4s[rr * 104 + n] = (_Float16)fmaxf(acc2[ct][r] + bias, 0.f);
      }
    }
  }
  __syncthreads();
  if (w < 2) {
    floatx4 acc3;
#pragma unroll
    for (int r = 0; r < 4; r++) acc3[r] = 0.f;
    const _Float16* A3 = h4s + (w * 16 + l16) * 104 + q * 8;
    for (int kc = 0; kc < 3; kc++) {
      half8 a = *(const half8*)(A3 + kc * 32);
      half8 b = *(const half8*)(wg + (size_t)l16 * 96 + kc * 32 + q * 8);
      acc3 = __builtin_amdgcn_mfma_f32_16x16x32_f16(a, b, acc3, 0, 0, 0);
    }
#pragma unroll
    for (int r = 0; r < 4; r++) {
      const int rr = w * 16 + q * 4 + r;
      zs[rr * 17 + l16] = acc3[r];
    }
  }
  __syncthreads();
  if (t < 32) {
    float e1 = 0.f, e2 = 0.f;
#pragma unroll
    for (int d = 0; d < 10; d++) {
      const float zv = zs[t * 17 + d];
      e1 += zv * al[d];
      e2 += zv * ar[d];
    }
    const float elv = e1 * LOG2E;
    el[row0 + t] = elv;
    er[row0 + t] = e2 * LOG2E;
    float m = elv;
#pragma unroll
    for (int off = 16; off > 0; off >>= 1)
      m = fmaxf(m, __shfl_down(m, off, 32));
    if (t == 0) atomicMax(emx, f2mono(m));
  }
  // zT[d][i] f16; row 10 = ones (denominator column)
  for (int idx = t; idx < 352; idx += 256) {
    const int d = idx >> 5, c = idx & 31;
    zT[(size_t)d * 8192 + row0 + c] =
        (d < 10) ? (_Float16)zs[c * 17 + d] : (_Float16)1.0f;
  }
}

// ---------------- attention via MFMA, fused with split-combine + bias.
// Block = 32 dst rows, 16 waves: wave w -> (isub = w&1, jslice = w>>1 of 8).
// Each wave: 32 MFMA over its 1024-j slice; partials to LDS; reduce; out.
__global__ __launch_bounds__(1024) void k_attn(const _Float16* __restrict__ zT,
    const float* __restrict__ el, const float* __restrict__ er,
    const unsigned* __restrict__ emx, const float* __restrict__ bg,
    float* __restrict__ out) {
  __shared__ float red[8][2][16][12];
  const int t = threadIdx.x;
  const int w = t >> 6, lane = t & 63;
  const int l16 = lane & 15, q = lane >> 4;
  const int isub = w & 1, js = w >> 1;
  const int row0 = blockIdx.x * 32;
  const int itile = row0 + isub * 16;
  const int jb = js * 1024;
  const float mx = mono2f(emx[0]);
  const float eri = er[itile + l16];
  const float s0 = eri + mx;
  const float mi = fmaxf(s0, 0.2f * s0);
  floatx4 acc;
#pragma unroll
  for (int r = 0; r < 4; r++) acc[r] = 0.f;
  const float* elp = el + jb + q * 8;
  const _Float16* ztp = zT + (size_t)l16 * 8192 + jb + q * 8;
  for (int jc = 0; jc < 32; jc++) {
    const float4 e0 = *(const float4*)(elp + jc * 32);
    const float4 e1 = *(const float4*)(elp + jc * 32 + 4);
    float wf[8];
    const float ej[8] = {e0.x, e0.y, e0.z, e0.w, e1.x, e1.y, e1.z, e1.w};
#pragma unroll
    for (int u = 0; u < 8; u++) {
      const float s = eri + ej[u];
      const float lr = fmaxf(s, 0.2f * s);
      wf[u] = exp2f(lr - mi);
    }
    half8 a;
#pragma unroll
    for (int u = 0; u < 8; u++) a[u] = (_Float16)wf[u];
    const half8 b = *(const half8*)(ztp + jc * 32);
    acc = __builtin_amdgcn_mfma_f32_16x16x32_f16(a, b, acc, 0, 0, 0);
  }
  if (l16 < 11) {
#pragma unroll
    for (int r = 0; r < 4; r++) red[js][isub][q * 4 + r][l16] = acc[r];
  }
  __syncthreads();
  if (t < 320) {
    const int ii = t / 10, d = t - (t / 10) * 10;
    const int i1 = ii >> 4, i2 = ii & 15;
    float num = 0.f, den = 0.f;
#pragma unroll
    for (int s = 0; s < 8; s++) {
      num += red[s][i1][i2][d];
      den += red[s][i1][i2][10];
    }
    out[(size_t)(row0 + ii) * 10 + d] = num / den + bg[d];
  }
}

extern "C" void kernel_launch(void* const* d_in, const int* in_sizes, int n_in,
                              void* d_out, int out_size, void* d_ws, size_t ws_size,
                              hipStream_t stream) {
  const float* x   = (const float*)d_in[0];
  const float* W1  = (const float*)d_in[1];
  const float* b1  = (const float*)d_in[2];
  const float* W2  = (const float*)d_in[3];
  const float* b2  = (const float*)d_in[4];
  const float* Wf1 = (const float*)d_in[5];
  const float* bf1 = (const float*)d_in[6];
  const float* Wf2 = (const float*)d_in[7];
  const float* bf2 = (const float*)d_in[8];
  const float* Wg  = (const float*)d_in[9];
  const float* al  = (const float*)d_in[10];
  const float* ar  = (const float*)d_in[11];
  const float* bg  = (const float*)d_in[12];
  float* out = (float*)d_out;

  float* ws = (float*)d_ws;
  float* p = ws + (size_t)8192 * 588;
  _Float16* h2f = (_Float16*)p;                         // 8192*416 f16
  p += (size_t)8192 * 208;
  _Float16* zTf = (_Float16*)p; p += 65536;             // 16*8192 f16
  float* el  = p; p += 8192;
  float* er  = p; p += 8192;
  unsigned* emx = (unsigned*)p; p += 16;
  _Float16* w1f = (_Float16*)p; p += 26624;             // 128*416 f16
  _Float16* w2f = (_Float16*)p; p += 6144;              // 96*128 f16
  _Float16* wgf = (_Float16*)p; p += 768;               // 16*96 f16
  _Float16* B1g = (_Float16*)p; p += 3072;              // 32*192 f16
  _Float16* B2g = (_Float16*)p; p += 2048;              // 16*256 f16

  k_prep<<<302, 256, 0, stream>>>(Wf1, Wf2, Wg, W1, W2, w1f, w2f, wgf, B1g, B2g, emx);
  k_convs<<<4096, 256, 0, stream>>>(x, B1g, b1, B2g, b2, h2f);
  k_mlp<<<256, 256, 0, stream>>>(h2f, w1f, bf1, w2f, bf2, wgf, al, ar, zTf, el, er, emx);
  k_attn<<<256, 1024, 0, stream>>>(zTf, el, er, emx, bg, out);
}

// Round 7
// 242.033 us; speedup vs baseline: 1.1546x; 1.1546x over previous
//
#include <hip/hip_runtime.h>
#include <hip/hip_bf16.h>

typedef _Float16 half8 __attribute__((ext_vector_type(8)));
typedef float floatx4 __attribute__((ext_vector_type(4)));

#define LOG2E 1.44269504088896340736f

// DPP cross-lane max within quads (pooling over corner = lane&3), no DS pipe
__device__ __forceinline__ float pool4_dpp(float v) {
  int s1 = __builtin_amdgcn_update_dpp(0, __float_as_int(v), 0xB1, 0xF, 0xF, true); // xor1
  float v1 = fmaxf(v, __int_as_float(s1));
  int s2 = __builtin_amdgcn_update_dpp(0, __float_as_int(v1), 0x4E, 0xF, 0xF, true); // xor2
  return fmaxf(v1, __int_as_float(s2));
}

// monotonic float<->uint mapping for atomicMax over signed floats
__device__ __forceinline__ unsigned f2mono(float f) {
  unsigned u = __float_as_uint(f);
  return (u & 0x80000000u) ? ~u : (u | 0x80000000u);
}
__device__ __forceinline__ float mono2f(unsigned u) {
  return (u & 0x80000000u) ? __uint_as_float(u & 0x7fffffffu)
                           : __uint_as_float(~u);
}

// ---------------- prep: f16 MLP weights + conv B-matrices (+ emx init)
__global__ __launch_bounds__(256) void k_prep(const float* __restrict__ Wf1,
    const float* __restrict__ Wf2, const float* __restrict__ Wg,
    const float* __restrict__ W1, const float* __restrict__ W2,
    _Float16* __restrict__ w1f, _Float16* __restrict__ w2f,
    _Float16* __restrict__ wgf, _Float16* __restrict__ B1,
    _Float16* __restrict__ B2M, unsigned* __restrict__ emx) {
  const int i = blockIdx.x * 256 + threadIdx.x;
  if (i == 0) emx[0] = 0u;  // f2mono lower bound
  if (i < 53248) {
    const int n = i / 416, k = i - n * 416;
    w1f[i] = (_Float16)((n < 120 && k < 400) ? Wf1[n * 400 + k] : 0.f);
  } else if (i < 65536) {
    const int j = i - 53248;
    const int n = j >> 7, k = j & 127;
    w2f[j] = (_Float16)((n < 84 && k < 120) ? Wf2[n * 120 + k] : 0.f);
  } else if (i < 67072) {
    const int g = i - 65536;
    const int n = g / 96, k = g - n * 96;
    wgf[g] = (_Float16)((n < 10 && k < 84) ? Wg[n * 84 + k] : 0.f);
  } else if (i < 73216) {
    const int g = i - 67072;
    const int n = g / 192, k = g - n * 192;
    const int co = n >> 2, cy = (n >> 1) & 1, cx = n & 1;
    const int pidx = k >> 3, j = k & 7;
    const int r = pidx >> 2, ci = pidx & 3;
    float v = 0.f;
    if (co < 6 && ci < 3) {
      const int ky = r - cy, kx = j - cx;
      if (ky >= 0 && ky < 5 && kx >= 0 && kx < 5)
        v = W1[((co * 3 + ci) * 5 + ky) * 5 + kx];
    }
    B1[g] = (_Float16)v;
  } else if (i < 77312) {
    const int g = i - 73216;
    const int n = g >> 8, k = g & 255;
    float v = 0.f;
    if (k < 240) {
      const int ci = k / 40, rem = k - ci * 40, r = rem >> 3, j = rem & 7;
      if (j < 5) v = W2[((n * 6 + ci) * 5 + r) * 5 + j];
    }
    B2M[g] = (_Float16)v;
  }
}

// ---------------- fused conv1+pool+conv2+pool: 2 images/block, 256 threads.
// LDS 17792 B; __launch_bounds__(256,6) -> VGPR budget ~80 (no spills,
// round-6's (256,8) forced VGPR=32 and spilled 25KB/block to scratch),
// 6 waves/SIMD = 6 blocks/CU (~75% occupancy).
// Single input copy (no alignment duplicate): A-fragments read as 4x ds_read_b32
// (4B-aligned always). Per image (stride 6544B):
//   conv1 staging: 3 ci x 2180B (32 rows x 68B = 32 cols f16 + 2 zero cols)
//   conv2 staging (ALIASES conv1 region after barrier): 6 ci x 1016B =
//     2 parity copies x 508B (14 rows x 36B), copy1 shifted by one f16
// h1 region at 13088: 2 img x 1176 f16 (2352B).
__global__ __launch_bounds__(256, 6) void k_convs(const float* __restrict__ x,
    const _Float16* __restrict__ B1, const float* __restrict__ b1,
    const _Float16* __restrict__ B2M, const float* __restrict__ b2,
    _Float16* __restrict__ h2) {
  __shared__ __align__(16) char sm[17792];
  _Float16* h1L = (_Float16*)(sm + 13088);
  const int t = threadIdx.x;
  const int n0 = blockIdx.x * 2;
  const int w4 = t >> 6, lane = t & 63;
  const int l16 = lane & 15, q = lane >> 4;

  // ---- phase 0: stage 2 input images, single f16 copy
  const float4* x4 = (const float4*)(x + (size_t)n0 * 3072);
  for (int i = t; i < 1536; i += 256) {
    const float4 v = x4[i];
    const int img = (i >= 768);
    const int ii = i - img * 768;
    const int ci = ii >> 8, rem2 = ii & 255;
    const int y = rem2 >> 3, c = rem2 & 7;
    union { _Float16 h[2]; unsigned u; } p01, p23;
    p01.h[0] = (_Float16)v.x; p01.h[1] = (_Float16)v.y;
    p23.h[0] = (_Float16)v.z; p23.h[1] = (_Float16)v.w;
    char* row = sm + img * 6544 + ci * 2180 + y * 68;
    *(unsigned*)(row + 8 * c) = p01.u;
    *(unsigned*)(row + 8 * c + 4) = p23.u;
  }
  if (t < 192) {  // zero cols 32,33 of each row (NaN guard for j>=5 taps)
    const int img = t / 96, tt = t - img * 96;
    const int ci = tt >> 5, y = tt & 31;
    *(unsigned*)(sm + img * 6544 + ci * 2180 + y * 68 + 64) = 0u;
  }
  if (t < 32) {  // h2 tail padding (cols 400..415)
    const int im = t >> 4;
    h2[(size_t)(n0 + im) * 416 + 400 + (t & 15)] = (_Float16)0.f;
  }
  __syncthreads();

  // ---- phase 1: conv1 + relu + pool -> h1 in LDS.
  // wave = (img = w4>>1, half = w4&1 -> 7 py rows). Two nt passes (n-tiles
  // 0..15 / 16..31) to halve live B-fragment registers.
  {
    const int img = w4 >> 1, wl = w4 & 1;
    const char* base = sm + img * 6544 + ((q == 3) ? 0 : q * 2180) + 4 * l16;
    const int py0 = wl * 7;
    const bool store_lane = (l16 & 3) == 0;
    for (int nt = 0; nt < 2; nt++) {
      const int co = nt * 4 + (l16 >> 2);
      half8 bfr[6];
#pragma unroll
      for (int kc = 0; kc < 6; kc++)
        bfr[kc] = *(const half8*)(B1 + (size_t)(nt * 16 + l16) * 192 + kc * 32 + q * 8);
      const float bias = (co < 6) ? b1[co] : 0.f;
      union AU { unsigned u[4]; half8 h; } a[6];
#pragma unroll
      for (int r = 0; r < 6; r++) {
        const char* rp = base + (2 * py0 + r) * 68;
        a[r].u[0] = *(const unsigned*)(rp);
        a[r].u[1] = *(const unsigned*)(rp + 4);
        a[r].u[2] = *(const unsigned*)(rp + 8);
        a[r].u[3] = *(const unsigned*)(rp + 12);
      }
      for (int py = py0; py < py0 + 7; ++py) {
        floatx4 acc;
#pragma unroll
        for (int r = 0; r < 4; r++) acc[r] = 0.f;
#pragma unroll
        for (int kc = 0; kc < 6; kc++)
          acc = __builtin_amdgcn_mfma_f32_16x16x32_f16(a[kc].h, bfr[kc], acc, 0, 0, 0);
        if (py < py0 + 6) {
          a[0] = a[2]; a[1] = a[3]; a[2] = a[4]; a[3] = a[5];
          const char* rp4 = base + (2 * py + 6) * 68;
          a[4].u[0] = *(const unsigned*)(rp4);
          a[4].u[1] = *(const unsigned*)(rp4 + 4);
          a[4].u[2] = *(const unsigned*)(rp4 + 8);
          a[4].u[3] = *(const unsigned*)(rp4 + 12);
          const char* rp5 = rp4 + 68;
          a[5].u[0] = *(const unsigned*)(rp5);
          a[5].u[1] = *(const unsigned*)(rp5 + 4);
          a[5].u[2] = *(const unsigned*)(rp5 + 8);
          a[5].u[3] = *(const unsigned*)(rp5 + 12);
        }
        float p0[4];
#pragma unroll
        for (int r = 0; r < 4; r++)
          p0[r] = fmaxf(pool4_dpp(acc[r]) + bias, 0.f);
        if (store_lane && co < 6) {
          union { _Float16 h[2]; unsigned u; } s01, s23;
          s01.h[0] = (_Float16)p0[0]; s01.h[1] = (_Float16)p0[1];
          s23.h[0] = (_Float16)p0[2]; s23.h[1] = (_Float16)p0[3];
          _Float16* dst = h1L + img * 1176 + co * 196 + py * 14 + q * 4;
          *(unsigned*)dst = s01.u;
          if (q < 3) *(unsigned*)(dst + 2) = s23.u;
        }
      }
    }
  }
  __syncthreads();

  // ---- phase 2: conv2 parity-staging (2 copies), overwrites conv1 region.
  // unit = (img, ci, y, g): writes dwords [4g,4g+4) of copy0 and copy1.
  for (int uu = t; uu < 336; uu += 256) {
    const int img = uu / 168, rem = uu - img * 168;
    const int ci = rem / 28, r2 = rem - ci * 28;
    const int y = r2 >> 1, g = r2 & 1;
    const unsigned* src = (const unsigned*)(h1L + img * 1176 + ci * 196 + y * 14);
    unsigned u5[5];
#pragma unroll
    for (int k = 0; k < 5; k++) {
      const int idx = 4 * g + k;
      u5[k] = (idx < 7) ? src[idx] : 0u;
    }
    char* b0 = sm + img * 6544 + ci * 1016 + y * 36 + 16 * g;
#pragma unroll
    for (int w = 0; w < 4; w++) {
      *(unsigned*)(b0 + 4 * w) = u5[w];
      *(unsigned*)(b0 + 508 + 4 * w) = (u5[w] >> 16) | (u5[w + 1] << 16);
    }
  }
  __syncthreads();

  // ---- phase 3: conv2 + relu + pool -> h2 global (13 m-tiles over 4 waves)
  {
    int C2[8];
#pragma unroll
    for (int kc = 0; kc < 8; kc++) {
      const int pidx = kc * 4 + q;
      C2[kc] = (pidx < 30) ? (pidx / 5) * 1016 + (pidx % 5) * 36 : 0;
    }
    const float bias2 = b2[l16];
    for (int mt = w4; mt < 13; mt += 4) {
      const int m = min(mt * 16 + l16, 199);
      const int pos = m >> 2, cy = (m >> 1) & 1, cx = m & 1;
      const int img = pos / 25, p = pos - img * 25;
      const int py = p / 5, px = p - py * 5;
      const char* base =
          sm + img * 6544 + cx * 508 + (2 * py + cy) * 36 + 4 * px;
      floatx4 acc;
#pragma unroll
      for (int r = 0; r < 4; r++) acc[r] = 0.f;
#pragma unroll
      for (int kc = 0; kc < 8; kc++) {
        union { unsigned u[4]; half8 h; } av;
        const char* ap = base + C2[kc];
        av.u[0] = *(const unsigned*)(ap);
        av.u[1] = *(const unsigned*)(ap + 4);
        av.u[2] = *(const unsigned*)(ap + 8);
        av.u[3] = *(const unsigned*)(ap + 12);
        const half8 bv = *(const half8*)(B2M + (size_t)l16 * 256 + kc * 32 + q * 8);
        acc = __builtin_amdgcn_mfma_f32_16x16x32_f16(av.h, bv, acc, 0, 0, 0);
      }
      const float v = fmaxf(fmaxf(acc[0], acc[1]), fmaxf(acc[2], acc[3]));
      const int posL = mt * 4 + q;
      if (posL < 50) {
        const int im = posL / 25, pp = posL - im * 25;
        h2[(size_t)(n0 + im) * 416 + l16 * 25 + pp] =
            (_Float16)fmaxf(v + bias2, 0.f);
      }
    }
  }
}

// ---------------- fused MLP via f16 MFMA; emits zT f16 [16][8192] (row10=ones),
// el/er pre-scaled by log2(e), and global el-max via atomicMax (mono encoding).
__global__ __launch_bounds__(256) void k_mlp(
    const _Float16* __restrict__ h2, const _Float16* __restrict__ w1,
    const float* __restrict__ bf1, const _Float16* __restrict__ w2,
    const float* __restrict__ bf2, const _Float16* __restrict__ wg,
    const float* __restrict__ al, const float* __restrict__ ar,
    _Float16* __restrict__ zT, float* __restrict__ el, float* __restrict__ er,
    unsigned* __restrict__ emx) {
  __shared__ __align__(16) _Float16 h3s[32 * 136];
  __shared__ __align__(16) _Float16 h4s[32 * 104];
  __shared__ float zs[32 * 17];
  const int t = threadIdx.x;
  const int w = t >> 6, lane = t & 63;
  const int l16 = lane & 15, q = lane >> 4;
  const int row0 = blockIdx.x * 32;
  for (int i = t; i < 2176; i += 256) ((float*)h3s)[i] = 0.f;
  for (int i = t; i < 1664; i += 256) ((float*)h4s)[i] = 0.f;
  const int rt = w & 1, cg = w >> 1;
  const int am = row0 + rt * 16 + l16;
  floatx4 acc[4];
#pragma unroll
  for (int ct = 0; ct < 4; ct++)
#pragma unroll
    for (int r = 0; r < 4; r++) acc[ct][r] = 0.f;
  const half8* Ag = (const half8*)(h2 + (size_t)am * 416 + q * 8);
  for (int kc = 0; kc < 13; kc++) {
    half8 a = Ag[kc * 4];
#pragma unroll
    for (int ct = 0; ct < 4; ct++) {
      const int n = cg * 64 + ct * 16 + l16;
      half8 b = *(const half8*)(w1 + (size_t)n * 416 + kc * 32 + q * 8);
      acc[ct] = __builtin_amdgcn_mfma_f32_16x16x32_f16(a, b, acc[ct], 0, 0, 0);
    }
  }
  __syncthreads();
#pragma unroll
  for (int ct = 0; ct < 4; ct++) {
    const int n = cg * 64 + ct * 16 + l16;
    if (n < 120) {
      const float bias = bf1[n];
#pragma unroll
      for (int r = 0; r < 4; r++) {
        const int rr = rt * 16 + q * 4 + r;
        h3s[rr * 136 + n] = (_Float16)fmaxf(acc[ct][r] + bias, 0.f);
      }
    }
  }
  __syncthreads();
  const int cbase2 = (w >> 1) * 3;
  floatx4 acc2[3];
#pragma unroll
  for (int ct = 0; ct < 3; ct++)
#pragma unroll
    for (int r = 0; r < 4; r++) acc2[ct][r] = 0.f;
  const _Float16* A2 = h3s + (rt * 16 + l16) * 136 + q * 8;
  for (int kc = 0; kc < 4; kc++) {
    half8 a = *(const half8*)(A2 + kc * 32);
#pragma unroll
    for (int ct = 0; ct < 3; ct++) {
      const int n = (cbase2 + ct) * 16 + l16;
      half8 b = *(const half8*)(w2 + (size_t)n * 128 + kc * 32 + q * 8);
      acc2[ct] = __builtin_amdgcn_mfma_f32_16x16x32_f16(a, b, acc2[ct], 0, 0, 0);
    }
  }
  __syncthreads();
#pragma unroll
  for (int ct = 0; ct < 3; ct++) {
    const int n = (cbase2 + ct) * 16 + l16;
    if (n < 84) {
      const float bias = bf2[n];
#pragma unroll
      for (int r = 0; r < 4; r++) {
        const int rr = rt * 16 + q * 4 + r;
        h4s[rr * 104 + n] = (_Float16)fmaxf(acc2[ct][r] + bias, 0.f);
      }
    }
  }
  __syncthreads();
  if (w < 2) {
    floatx4 acc3;
#pragma unroll
    for (int r = 0; r < 4; r++) acc3[r] = 0.f;
    const _Float16* A3 = h4s + (w * 16 + l16) * 104 + q * 8;
    for (int kc = 0; kc < 3; kc++) {
      half8 a = *(const half8*)(A3 + kc * 32);
      half8 b = *(const half8*)(wg + (size_t)l16 * 96 + kc * 32 + q * 8);
      acc3 = __builtin_amdgcn_mfma_f32_16x16x32_f16(a, b, acc3, 0, 0, 0);
    }
#pragma unroll
    for (int r = 0; r < 4; r++) {
      const int rr = w * 16 + q * 4 + r;
      zs[rr * 17 + l16] = acc3[r];
    }
  }
  __syncthreads();
  if (t < 32) {
    float e1 = 0.f, e2 = 0.f;
#pragma unroll
    for (int d = 0; d < 10; d++) {
      const float zv = zs[t * 17 + d];
      e1 += zv * al[d];
      e2 += zv * ar[d];
    }
    const float elv = e1 * LOG2E;
    el[row0 + t] = elv;
    er[row0 + t] = e2 * LOG2E;
    float m = elv;
#pragma unroll
    for (int off = 16; off > 0; off >>= 1)
      m = fmaxf(m, __shfl_down(m, off, 32));
    if (t == 0) atomicMax(emx, f2mono(m));
  }
  // zT[d][i] f16; row 10 = ones (denominator column)
  for (int idx = t; idx < 352; idx += 256) {
    const int d = idx >> 5, c = idx & 31;
    zT[(size_t)d * 8192 + row0 + c] =
        (d < 10) ? (_Float16)zs[c * 17 + d] : (_Float16)1.0f;
  }
}

// ---------------- attention via MFMA, fused with split-combine + bias.
// Block = 32 dst rows, 16 waves: wave w -> (isub = w&1, jslice = w>>1 of 8).
// Each wave: 32 MFMA over its 1024-j slice; partials to LDS; reduce; out.
__global__ __launch_bounds__(1024) void k_attn(const _Float16* __restrict__ zT,
    const float* __restrict__ el, const float* __restrict__ er,
    const unsigned* __restrict__ emx, const float* __restrict__ bg,
    float* __restrict__ out) {
  __shared__ float red[8][2][16][12];
  const int t = threadIdx.x;
  const int w = t >> 6, lane = t & 63;
  const int l16 = lane & 15, q = lane >> 4;
  const int isub = w & 1, js = w >> 1;
  const int row0 = blockIdx.x * 32;
  const int itile = row0 + isub * 16;
  const int jb = js * 1024;
  const float mx = mono2f(emx[0]);
  const float eri = er[itile + l16];
  const float s0 = eri + mx;
  const float mi = fmaxf(s0, 0.2f * s0);
  floatx4 acc;
#pragma unroll
  for (int r = 0; r < 4; r++) acc[r] = 0.f;
  const float* elp = el + jb + q * 8;
  const _Float16* ztp = zT + (size_t)l16 * 8192 + jb + q * 8;
  for (int jc = 0; jc < 32; jc++) {
    const float4 e0 = *(const float4*)(elp + jc * 32);
    const float4 e1 = *(const float4*)(elp + jc * 32 + 4);
    float wf[8];
    const float ej[8] = {e0.x, e0.y, e0.z, e0.w, e1.x, e1.y, e1.z, e1.w};
#pragma unroll
    for (int u = 0; u < 8; u++) {
      const float s = eri + ej[u];
      const float lr = fmaxf(s, 0.2f * s);
      wf[u] = exp2f(lr - mi);
    }
    half8 a;
#pragma unroll
    for (int u = 0; u < 8; u++) a[u] = (_Float16)wf[u];
    const half8 b = *(const half8*)(ztp + jc * 32);
    acc = __builtin_amdgcn_mfma_f32_16x16x32_f16(a, b, acc, 0, 0, 0);
  }
  if (l16 < 11) {
#pragma unroll
    for (int r = 0; r < 4; r++) red[js][isub][q * 4 + r][l16] = acc[r];
  }
  __syncthreads();
  if (t < 320) {
    const int ii = t / 10, d = t - (t / 10) * 10;
    const int i1 = ii >> 4, i2 = ii & 15;
    float num = 0.f, den = 0.f;
#pragma unroll
    for (int s = 0; s < 8; s++) {
      num += red[s][i1][i2][d];
      den += red[s][i1][i2][10];
    }
    out[(size_t)(row0 + ii) * 10 + d] = num / den + bg[d];
  }
}

extern "C" void kernel_launch(void* const* d_in, const int* in_sizes, int n_in,
                              void* d_out, int out_size, void* d_ws, size_t ws_size,
                              hipStream_t stream) {
  const float* x   = (const float*)d_in[0];
  const float* W1  = (const float*)d_in[1];
  const float* b1  = (const float*)d_in[2];
  const float* W2  = (const float*)d_in[3];
  const float* b2  = (const float*)d_in[4];
  const float* Wf1 = (const float*)d_in[5];
  const float* bf1 = (const float*)d_in[6];
  const float* Wf2 = (const float*)d_in[7];
  const float* bf2 = (const float*)d_in[8];
  const float* Wg  = (const float*)d_in[9];
  const float* al  = (const float*)d_in[10];
  const float* ar  = (const float*)d_in[11];
  const float* bg  = (const float*)d_in[12];
  float* out = (float*)d_out;

  float* ws = (float*)d_ws;
  float* p = ws + (size_t)8192 * 588;
  _Float16* h2f = (_Float16*)p;                         // 8192*416 f16
  p += (size_t)8192 * 208;
  _Float16* zTf = (_Float16*)p; p += 65536;             // 16*8192 f16
  float* el  = p; p += 8192;
  float* er  = p; p += 8192;
  unsigned* emx = (unsigned*)p; p += 16;
  _Float16* w1f = (_Float16*)p; p += 26624;             // 128*416 f16
  _Float16* w2f = (_Float16*)p; p += 6144;              // 96*128 f16
  _Float16* wgf = (_Float16*)p; p += 768;               // 16*96 f16
  _Float16* B1g = (_Float16*)p; p += 3072;              // 32*192 f16
  _Float16* B2g = (_Float16*)p; p += 2048;              // 16*256 f16

  k_prep<<<302, 256, 0, stream>>>(Wf1, Wf2, Wg, W1, W2, w1f, w2f, wgf, B1g, B2g, emx);
  k_convs<<<4096, 256, 0, stream>>>(x, B1g, b1, B2g, b2, h2f);
  k_mlp<<<256, 256, 0, stream>>>(h2f, w1f, bf1, w2f, bf2, wgf, al, ar, zTf, el, er, emx);
  k_attn<<<256, 1024, 0, stream>>>(zTf, el, er, emx, bg, out);
}